// Round 13
// baseline (147.729 us; speedup 1.0000x reference)
//
#include <hip/hip_runtime.h>
#include <stdint.h>

typedef __attribute__((ext_vector_type(8))) short short8;
typedef __attribute__((ext_vector_type(4))) short short4v;
typedef __attribute__((ext_vector_type(4))) float f32x4;
typedef __attribute__((ext_vector_type(16))) float f32x16;
typedef __attribute__((ext_vector_type(4))) int int4v;

static __device__ __forceinline__ unsigned short f2b(float f) {
  unsigned int u = __builtin_bit_cast(unsigned int, f);
  u += 0x7fffu + ((u >> 16) & 1u);
  return (unsigned short)(u >> 16);
}
static __device__ __forceinline__ float b2f(unsigned short b) {
  unsigned int u = ((unsigned int)b) << 16;
  return __builtin_bit_cast(float, u);
}

#define GLD16(gp, lp)                                                          \
  __builtin_amdgcn_global_load_lds(                                            \
      (const __attribute__((address_space(1))) void*)(gp),                     \
      (__attribute__((address_space(3))) void*)(lp), 16, 0, 0)

#define MFMA16 __builtin_amdgcn_mfma_f32_16x16x32_bf16
#define MFMA32 __builtin_amdgcn_mfma_f32_32x32x16_bf16

#define CVTPK(dst, lo, hi)                                                     \
  asm("v_cvt_pk_bf16_f32 %0, %1, %2" : "=v"(dst) : "v"(lo), "v"(hi))
#define PLSWAP(x, y)                                                           \
  asm volatile("v_permlane32_swap_b32 %0, %1" : "+v"(x), "+v"(y))

// QSC = 0.125 * log2(e); C2 = 0.0625 * log2(e)
#define QSC 0.18033688011112113f
#define C2 0.09016844005556057f

// ---------------- fp32 -> bf16 convert: weights only ----------------------
__global__ void cvtw_kernel(const float* __restrict__ Wd,
                            const float* __restrict__ Wq,
                            const float* __restrict__ Wk,
                            const float* __restrict__ Wv,
                            unsigned short* __restrict__ Wcq,
                            unsigned short* __restrict__ Wck) {
  const int bx = blockIdx.x;
  const int seg = bx / 576;
  const int i = (bx - seg * 576) * 256 + threadIdx.x;
  const float* src;
  unsigned short* dst;
  switch (seg) {
    case 0: src = Wd; dst = Wcq; break;
    case 1: src = Wq; dst = Wcq + 589824; break;
    case 2: src = Wd; dst = Wck; break;
    case 3: src = Wk; dst = Wck + 589824; break;
    default: src = Wv; dst = Wck + 1179648; break;
  }
  float4 v = reinterpret_cast<const float4*>(src)[i];
  short4v o;
  o.x = (short)f2b(v.x);
  o.y = (short)f2b(v.y);
  o.z = (short)f2b(v.z);
  o.w = (short)f2b(v.w);
  reinterpret_cast<short4v*>(dst)[i] = o;
}

// ---------------- fused projection GEMM: 128x256 tile, 8 waves ------------
// grid (64, 15): by<6 -> query path (q fp32 x Wcq), else key path.
// A-operand: fp32 from the INPUT, 2-iteration-deep register prefetch
// (load A(t+2) at top, cvt+ds_write A(t+1) at bottom), end-of-iter
// s_waitcnt vmcnt(2) + raw s_barrier leaves the newest A-pair in flight
// while draining B(t+1) (issued before it) and the ds_write (lgkmcnt 0).
// B-operand: bf16 weights via global_load_lds. kdsq->wq on key/mat-0.
__global__ __launch_bounds__(512, 4) void proj_kernel(
    const float* __restrict__ Xqf, const float* __restrict__ Xkf,
    const unsigned short* __restrict__ Wcq, const unsigned short* __restrict__ Wck,
    const float* __restrict__ bq, const float* __restrict__ bk,
    const float* __restrict__ bv, unsigned short* __restrict__ Qc,
    unsigned short* __restrict__ Kc, unsigned short* __restrict__ Vt,
    float* __restrict__ wqf) {
  __shared__ __align__(16) short lds[2][384 * 32];  // 48 KB: A 128 rows, B 256
  const int by = blockIdx.y;
  const bool mode0 = (by < 6);
  const float* Xf = mode0 ? Xqf : Xkf;
  const unsigned short* W = mode0 ? Wcq : Wck;
  const int col0 = (mode0 ? by : by - 6) * 256;
  const int row0 = blockIdx.x * 128;
  const int tid = threadIdx.x;
  const int lane = tid & 63;
  const int wid = tid >> 6;
  const int wm = wid >> 2;   // 0..1 (M: 64-row strip)
  const int wn = wid & 3;    // 0..3 (N: 64-col strip)
  const int l15 = lane & 15, l4 = lane >> 4;
  const int RSWZ = (l4 ^ ((l15 >> 1) & 3)) << 4;

  f32x4 acc[4][4];
#pragma unroll
  for (int i = 0; i < 4; ++i)
#pragma unroll
    for (int j = 0; j < 4; ++j) acc[i][j] = (f32x4){0.f, 0.f, 0.f, 0.f};

  // A: slot c = tid (128 rows x 4 slots); source pre-swizzled (round 9).
  const int Ar = tid >> 2;
  const int Asl = (tid & 3) ^ ((tid >> 3) & 3);
  const float* Agp = Xf + (size_t)(row0 + Ar) * 768 + Asl * 8;

  auto loadA = [&](int k0, float4& a0, float4& a1) {
    a0 = *reinterpret_cast<const float4*>(Agp + k0);
    a1 = *reinterpret_cast<const float4*>(Agp + k0 + 4);
  };
  auto writeA = [&](int bufi, const float4& a0, const float4& a1) {
    unsigned int u0, u1, u2, u3;
    CVTPK(u0, a0.x, a0.y);
    CVTPK(u1, a0.z, a0.w);
    CVTPK(u2, a1.x, a1.y);
    CVTPK(u3, a1.z, a1.w);
    int4v v = {(int)u0, (int)u1, (int)u2, (int)u3};
    *reinterpret_cast<int4v*>((char*)&lds[bufi][0] + (size_t)tid * 16) = v;
  };
  auto stageB = [&](int bufi, int k0) {
#pragma unroll
    for (int iss = 0; iss < 2; ++iss) {
      const int c = iss * 512 + tid;
      const int r = c >> 2;
      const int sl = (c & 3) ^ ((c >> 3) & 3);
      const unsigned short* gp = W + (size_t)(col0 + r) * 768 + k0 + sl * 8;
      GLD16(gp, (char*)&lds[bufi][0] + 8192 + (size_t)c * 16);
    }
  };

  // One K-step: stage B(t+1), load A(t+2) into (tA0,tA1), compute buf(t),
  // write A(t+1) from (sA0,sA1), counted wait + raw barrier.
  auto step = [&](int kt, int bufc, float4& tA0, float4& tA1, float4& sA0,
                  float4& sA1) {
    if (kt < 23) stageB(bufc ^ 1, (kt + 1) * 32);
    if (kt < 22) loadA((kt + 2) * 32, tA0, tA1);

    const char* Ab = (const char*)&lds[bufc][0];
    const char* Bb = (const char*)&lds[bufc][0] + 8192;
    short8 a[4], b[4];
#pragma unroll
    for (int mt = 0; mt < 4; ++mt) {
      const int r = wm * 64 + mt * 16 + l15;
      a[mt] = *reinterpret_cast<const short8*>(Ab + r * 64 + RSWZ);
    }
#pragma unroll
    for (int nt = 0; nt < 4; ++nt) {
      const int r = wn * 64 + nt * 16 + l15;
      b[nt] = *reinterpret_cast<const short8*>(Bb + r * 64 + RSWZ);
    }
    __builtin_amdgcn_s_setprio(1);
#pragma unroll
    for (int mt = 0; mt < 4; ++mt)
#pragma unroll
      for (int nt = 0; nt < 4; ++nt)
        acc[mt][nt] = MFMA16(a[mt], b[nt], acc[mt][nt], 0, 0, 0);
    __builtin_amdgcn_s_setprio(0);
    if (kt < 23) writeA(bufc ^ 1, sA0, sA1);
    if (kt < 22) {
      // newest 2 VMEM = A(t+2) loads; B(t+1) (older) drained; ds ops drained
      asm volatile("s_waitcnt vmcnt(2) lgkmcnt(0)" ::: "memory");
    } else {
      asm volatile("s_waitcnt vmcnt(0) lgkmcnt(0)" ::: "memory");
    }
    __builtin_amdgcn_s_barrier();
  };

  float4 xa0_0, xa0_1, xa1_0, xa1_1;  // parity register sets (A even/odd)
  // prologue: A(0) -> buf0 now; A(1) in flight
  loadA(0, xa0_0, xa0_1);
  stageB(0, 0);
  asm volatile("s_waitcnt vmcnt(2)" ::: "memory");  // A(0) landed
  writeA(0, xa0_0, xa0_1);
  loadA(32, xa1_0, xa1_1);  // A(1)
  asm volatile("s_waitcnt vmcnt(2) lgkmcnt(0)" ::: "memory");  // B(0) landed
  __builtin_amdgcn_s_barrier();

  for (int k2 = 0; k2 < 12; ++k2) {
    const int kt0 = 2 * k2;
    step(kt0, 0, xa0_0, xa0_1, xa1_0, xa1_1);      // even: load A->xa0, write xa1
    step(kt0 + 1, 1, xa1_0, xa1_1, xa0_0, xa0_1);  // odd: load A->xa1, write xa0
  }

  const int mat = mode0 ? (col0 >= 768 ? 1 : 0) : ((by - 6) / 3);

  // ---- kdsq -> wq (key path, mat 0: kd cols). Head = 64-col wn strip. ----
  if (!mode0 && mat == 0) {
    const int hh = ((by - 6) << 2) + wn;  // 0..11
#pragma unroll
    for (int mt = 0; mt < 4; ++mt) {
#pragma unroll
      for (int i = 0; i < 4; ++i) {
        float s = acc[mt][0][i] * acc[mt][0][i] + acc[mt][1][i] * acc[mt][1][i] +
                  acc[mt][2][i] * acc[mt][2][i] + acc[mt][3][i] * acc[mt][3][i];
        s += __shfl_xor(s, 1);
        s += __shfl_xor(s, 2);
        s += __shfl_xor(s, 4);
        s += __shfl_xor(s, 8);
        if (l15 == 0) {
          const int row = row0 + wm * 64 + mt * 16 + l4 * 4 + i;
          const int bb = row >> 10, nn = row & 1023;
          wqf[(size_t)(bb * 12 + hh) * 1024 + nn] =
              __builtin_amdgcn_exp2f(-s * C2);
        }
      }
    }
  }

  // ---- epilogue: direct scatter (replay-proven); Vt packs short4 ----
  const int cbase = col0 - mat * 768 + wn * 64;
  const float* barr = mode0 ? bq : (mat == 2 ? bv : bk);
  if (!mode0 && mat == 2) {
#pragma unroll
    for (int nt = 0; nt < 4; ++nt) {
      const int cc = cbase + nt * 16 + l15;
      const int hh = cc >> 6, dd = cc & 63;
      const float bias = barr[cc];
#pragma unroll
      for (int mt = 0; mt < 4; ++mt) {
        const int row = row0 + wm * 64 + mt * 16 + l4 * 4;
        const int bb = row >> 10, nn = row & 1023;
        short4v pv;
#pragma unroll
        for (int i = 0; i < 4; ++i)
          pv[i] = (short)f2b(acc[mt][nt][i] + bias);
        *reinterpret_cast<short4v*>(
            Vt + ((size_t)(bb * 12 + hh) * 64 + dd) * 1024 + nn) = pv;
      }
    }
  } else {
    const float scale = mode0 ? QSC : 1.0f;
    unsigned short* outC = mode0 ? Qc : Kc;
#pragma unroll
    for (int nt = 0; nt < 4; ++nt) {
      const int cc = cbase + nt * 16 + l15;
      const int hh = cc >> 6, dd = cc & 63;
      const float bias = (mat >= 1) ? barr[cc] : 0.f;
#pragma unroll
      for (int mt = 0; mt < 4; ++mt) {
#pragma unroll
        for (int i = 0; i < 4; ++i) {
          const int row = row0 + wm * 64 + mt * 16 + l4 * 4 + i;
          const int bb = row >> 10, nn = row & 1023;
          outC[((size_t)(bb * 12 + hh) * 1024 + nn) * 128 + mat * 64 + dd] =
              f2b((acc[mt][nt][i] + bias) * scale);
        }
      }
    }
  }
}

// ---------------- flash attention: swapped-QK 32x32, in-register softmax --
// V is UNSCALED; w applied to P in-register: P = exp2(s - m) * w[key].
__global__ __launch_bounds__(256, 3) void attn_kernel(
    const unsigned short* __restrict__ Qc, const unsigned short* __restrict__ Kc,
    const unsigned short* __restrict__ Vt, const float* __restrict__ wqf,
    float* __restrict__ out) {
  __shared__ __align__(16) short kbuf[2][64 * 128];  // 32 KB, swz (row&15)<<4
  __shared__ __align__(16) short vbuf[2][64 * 64];   // 16 KB, swz (row&7)<<4
  __shared__ __align__(16) float wfb[1024];          // 4 KB

  const int bh = blockIdx.x % 96;
  const int qb = blockIdx.x / 96;
  const int b = bh / 12, h = bh - b * 12;
  const int lane = threadIdx.x & 63;
  const int w = threadIdx.x >> 6;
  const int l31 = lane & 31, l5 = lane >> 5;

  const unsigned short* Kg = Kc + (size_t)bh * 1024 * 128;
  const unsigned short* Vg = Vt + (size_t)bh * 64 * 1024;

  auto stageK = [&](int bufi, int kb) {
#pragma unroll
    for (int i = 0; i < 4; ++i) {
      const int slot = i * 256 + threadIdx.x;
      const int row = slot >> 4;
      const int d0 = ((slot & 15) ^ (row & 15)) * 8;
      const unsigned short* gp = Kg + (size_t)(kb * 64 + row) * 128 + d0;
      GLD16(gp, (char*)(&kbuf[bufi][0]) + (i * 256 + w * 64) * 16);
    }
  };
  auto stageV = [&](int bufi, int kb) {
#pragma unroll
    for (int i = 0; i < 2; ++i) {
      const int slot = i * 256 + threadIdx.x;
      const int row = slot >> 3;
      const int k0 = ((slot & 7) ^ (row & 7)) * 8;
      const unsigned short* gp = Vg + (size_t)row * 1024 + kb * 64 + k0;
      GLD16(gp, (char*)(&vbuf[bufi][0]) + (i * 256 + w * 64) * 16);
    }
  };

  stageK(0, 0);
  stageV(0, 0);
  {
    const float* gp = wqf + (size_t)bh * 1024 + threadIdx.x * 4;
    GLD16(gp, (char*)(&wfb[0]) + w * 1024);
  }

  const unsigned short* Qb =
      Qc + ((size_t)bh * 1024 + qb * 128 + w * 32 + l31) * 128 + l5 * 8;
  short8 qf[8];
#pragma unroll
  for (int s = 0; s < 8; ++s)
    qf[s] = *reinterpret_cast<const short8*>(Qb + s * 16);

  short8 ones;
#pragma unroll
  for (int j = 0; j < 8; ++j) ones[j] = (short)0x3F80;  // bf16 1.0

  f32x16 o0, o1, la;
#pragma unroll
  for (int r = 0; r < 16; ++r) {
    o0[r] = 0.f;
    o1[r] = 0.f;
    la[r] = 0.f;
  }
  float m = -1e30f;

  const int S4 = (lane & 15) << 4;
  const int S3 = (lane & 7) << 4;
  const int ko = l5 * 16;

  asm volatile("s_waitcnt vmcnt(0)" ::: "memory");
  __syncthreads();

  int buf = 0;
  for (int kb = 0; kb < 16; ++kb) {
    if (kb < 15) {
      stageK(buf ^ 1, kb + 1);
      stageV(buf ^ 1, kb + 1);
    }

    const char* kB = (const char*)(&kbuf[buf][0]) + l31 * 256;
    f32x16 s0, s1;
#pragma unroll
    for (int r = 0; r < 16; ++r) {
      s0[r] = 0.f;
      s1[r] = 0.f;
    }
    __builtin_amdgcn_s_setprio(1);
#pragma unroll
    for (int s = 0; s < 8; ++s) {
      const int off = (s * 32 + ko) ^ S4;
      short8 a0 = *reinterpret_cast<const short8*>(kB + off);
      short8 a1 = *reinterpret_cast<const short8*>(kB + 8192 + off);
      s0 = MFMA32(a0, qf[s], s0, 0, 0, 0);
      s1 = MFMA32(a1, qf[s], s1, 0, 0, 0);
    }
    __builtin_amdgcn_s_setprio(0);

    // per-key w vectors (broadcast f32x4 reads; rows crow = (r&3)+8(r>>2)+4l5)
    f32x4 w0v[4], w1v[4];
#pragma unroll
    for (int j = 0; j < 4; ++j) {
      w0v[j] = *reinterpret_cast<const f32x4*>(&wfb[kb * 64 + j * 8 + 4 * l5]);
      w1v[j] =
          *reinterpret_cast<const f32x4*>(&wfb[kb * 64 + 32 + j * 8 + 4 * l5]);
    }

    float mx = s0[0];
#pragma unroll
    for (int r = 1; r < 16; ++r) mx = fmaxf(mx, s0[r]);
#pragma unroll
    for (int r = 0; r < 16; ++r) mx = fmaxf(mx, s1[r]);
    mx = fmaxf(mx, __shfl_xor(mx, 32));

    if (!__all(mx <= m + 11.0f)) {
      const float mn = fmaxf(m, mx);
      const float c = __builtin_amdgcn_exp2f(m - mn);
      m = mn;
      float cr[16];
#pragma unroll
      for (int r = 0; r < 16; ++r)
        cr[r] = __shfl(c, (r & 3) + 8 * (r >> 2) + 4 * l5);
#pragma unroll
      for (int r = 0; r < 16; ++r) {
        la[r] *= cr[r];
        o0[r] *= cr[r];
        o1[r] *= cr[r];
      }
    }

#pragma unroll
    for (int r = 0; r < 16; ++r) {
      s0[r] = __builtin_amdgcn_exp2f(s0[r] - m) * w0v[r >> 2][r & 3];
      s1[r] = __builtin_amdgcn_exp2f(s1[r] - m) * w1v[r >> 2][r & 3];
    }
    unsigned int u[16];
#pragma unroll
    for (int j = 0; j < 8; ++j) {
      CVTPK(u[j], s0[2 * j], s0[2 * j + 1]);
      CVTPK(u[8 + j], s1[2 * j], s1[2 * j + 1]);
    }
    PLSWAP(u[0], u[2]);
    PLSWAP(u[1], u[3]);
    PLSWAP(u[4], u[6]);
    PLSWAP(u[5], u[7]);
    PLSWAP(u[8], u[10]);
    PLSWAP(u[9], u[11]);
    PLSWAP(u[12], u[14]);
    PLSWAP(u[13], u[15]);
    short8 pa[4];
    {
      int4v t0 = {(int)u[0], (int)u[1], (int)u[2], (int)u[3]};
      int4v t1 = {(int)u[4], (int)u[5], (int)u[6], (int)u[7]};
      int4v t2 = {(int)u[8], (int)u[9], (int)u[10], (int)u[11]};
      int4v t3 = {(int)u[12], (int)u[13], (int)u[14], (int)u[15]};
      pa[0] = __builtin_bit_cast(short8, t0);
      pa[1] = __builtin_bit_cast(short8, t1);
      pa[2] = __builtin_bit_cast(short8, t2);
      pa[3] = __builtin_bit_cast(short8, t3);
    }

    const char* vB = (const char*)(&vbuf[buf][0]) + l31 * 128;
    __builtin_amdgcn_s_setprio(1);
#pragma unroll
    for (int kk = 0; kk < 4; ++kk) {
      const int off = (kk * 32 + ko) ^ S3;
      short8 v0 = *reinterpret_cast<const short8*>(vB + off);
      short8 v1 = *reinterpret_cast<const short8*>(vB + 4096 + off);
      o0 = MFMA32(pa[kk], v0, o0, 0, 0, 0);
      o1 = MFMA32(pa[kk], v1, o1, 0, 0, 0);
      la = MFMA32(pa[kk], ones, la, 0, 0, 0);
    }
    __builtin_amdgcn_s_setprio(0);

    asm volatile("s_waitcnt vmcnt(0)" ::: "memory");
    __syncthreads();
    buf ^= 1;
  }

  const int qbase = b * 1024 + qb * 128 + w * 32;
#pragma unroll
  for (int r = 0; r < 16; ++r) {
    const float iv = __builtin_amdgcn_rcpf(la[r]);
    const int q = qbase + (r & 3) + 8 * (r >> 2) + 4 * l5;
    float* op = out + (size_t)q * 768 + h * 64 + l31;
    op[0] = o0[r] * iv;
    op[32] = o1[r] * iv;
  }
}

// ---------------------------------------------------------------------------
extern "C" void kernel_launch(void* const* d_in, const int* in_sizes, int n_in,
                              void* d_out, int out_size, void* d_ws,
                              size_t ws_size, hipStream_t stream) {
  const float* query = (const float*)d_in[0];
  const float* key = (const float*)d_in[1];
  const float* Wd = (const float*)d_in[2];
  const float* Wq = (const float*)d_in[3];
  const float* bq = (const float*)d_in[4];
  const float* Wk = (const float*)d_in[5];
  const float* bk = (const float*)d_in[6];
  const float* Wv = (const float*)d_in[7];
  const float* bv = (const float*)d_in[8];
  float* out = (float*)d_out;

  char* p = (char*)d_ws;
  auto alloc = [&](size_t n) {
    char* r = p;
    p += (n + 255) & ~(size_t)255;
    return r;
  };
  unsigned short* Wcq = (unsigned short*)alloc(1536ULL * 768 * 2);
  unsigned short* Wck = (unsigned short*)alloc(2304ULL * 768 * 2);
  unsigned short* Qc = (unsigned short*)alloc(96ULL * 1024 * 128 * 2);
  unsigned short* Kc = (unsigned short*)alloc(96ULL * 1024 * 128 * 2);
  unsigned short* Vt = (unsigned short*)alloc(96ULL * 64 * 1024 * 2);
  float* wqf = (float*)alloc(96ULL * 1024 * 4);

  cvtw_kernel<<<2880, 256, 0, stream>>>(Wd, Wq, Wk, Wv, Wcq, Wck);

  proj_kernel<<<dim3(64, 15), 512, 0, stream>>>(query, key, Wcq, Wck, bq, bk,
                                                bv, Qc, Kc, Vt, wqf);

  attn_kernel<<<768, 256, 0, stream>>>(Qc, Kc, Vt, wqf, out);
}

// Round 14
// 139.846 us; speedup vs baseline: 1.0564x; 1.0564x over previous
//
#include <hip/hip_runtime.h>
#include <stdint.h>

typedef __attribute__((ext_vector_type(8))) short short8;
typedef __attribute__((ext_vector_type(4))) short short4v;
typedef __attribute__((ext_vector_type(4))) float f32x4;
typedef __attribute__((ext_vector_type(16))) float f32x16;
typedef __attribute__((ext_vector_type(4))) int int4v;

static __device__ __forceinline__ unsigned short f2b(float f) {
  unsigned int u = __builtin_bit_cast(unsigned int, f);
  u += 0x7fffu + ((u >> 16) & 1u);
  return (unsigned short)(u >> 16);
}
static __device__ __forceinline__ float b2f(unsigned short b) {
  unsigned int u = ((unsigned int)b) << 16;
  return __builtin_bit_cast(float, u);
}

#define GLD16(gp, lp)                                                          \
  __builtin_amdgcn_global_load_lds(                                            \
      (const __attribute__((address_space(1))) void*)(gp),                     \
      (__attribute__((address_space(3))) void*)(lp), 16, 0, 0)

#define MFMA16 __builtin_amdgcn_mfma_f32_16x16x32_bf16
#define MFMA32 __builtin_amdgcn_mfma_f32_32x32x16_bf16

#define CVTPK(dst, lo, hi)                                                     \
  asm("v_cvt_pk_bf16_f32 %0, %1, %2" : "=v"(dst) : "v"(lo), "v"(hi))
#define PLSWAP(x, y)                                                           \
  asm volatile("v_permlane32_swap_b32 %0, %1" : "+v"(x), "+v"(y))

// QSC = 0.125 * log2(e); C2 = 0.0625 * log2(e)
#define QSC 0.18033688011112113f
#define C2 0.09016844005556057f

// ---------------- fp32 -> bf16 convert: weights only ----------------------
__global__ void cvtw_kernel(const float* __restrict__ Wd,
                            const float* __restrict__ Wq,
                            const float* __restrict__ Wk,
                            const float* __restrict__ Wv,
                            unsigned short* __restrict__ Wcq,
                            unsigned short* __restrict__ Wck) {
  const int bx = blockIdx.x;
  const int seg = bx / 576;
  const int i = (bx - seg * 576) * 256 + threadIdx.x;
  const float* src;
  unsigned short* dst;
  switch (seg) {
    case 0: src = Wd; dst = Wcq; break;
    case 1: src = Wq; dst = Wcq + 589824; break;
    case 2: src = Wd; dst = Wck; break;
    case 3: src = Wk; dst = Wck + 589824; break;
    default: src = Wv; dst = Wck + 1179648; break;
  }
  float4 v = reinterpret_cast<const float4*>(src)[i];
  short4v o;
  o.x = (short)f2b(v.x);
  o.y = (short)f2b(v.y);
  o.z = (short)f2b(v.z);
  o.w = (short)f2b(v.w);
  reinterpret_cast<short4v*>(dst)[i] = o;
}

// ---------------- fused projection GEMM: 128x256 tile, 8 waves ------------
// grid (64, 15): by<6 -> query path (q fp32 x Wcq), else key path.
// A-operand: fp32 loaded from the INPUT directly, converted in-register,
// ds_write'd into the staging buffer (issue-early / write-late, T14).
// B-operand: bf16 weights via global_load_lds. K-loop & scatter epilogue
// identical to round 9 (fastest verified). Key/mat-0 blocks additionally
// compute wq[bh][n] = exp2(-|kd|^2 * C2) from the f32 accumulators.
__global__ __launch_bounds__(512, 4) void proj_kernel(
    const float* __restrict__ Xqf, const float* __restrict__ Xkf,
    const unsigned short* __restrict__ Wcq, const unsigned short* __restrict__ Wck,
    const float* __restrict__ bq, const float* __restrict__ bk,
    const float* __restrict__ bv, unsigned short* __restrict__ Qc,
    unsigned short* __restrict__ Kc, unsigned short* __restrict__ Vt,
    float* __restrict__ wqf) {
  __shared__ __align__(16) short lds[2][384 * 32];  // 48 KB: A 128 rows, B 256
  const int by = blockIdx.y;
  const bool mode0 = (by < 6);
  const float* Xf = mode0 ? Xqf : Xkf;
  const unsigned short* W = mode0 ? Wcq : Wck;
  const int col0 = (mode0 ? by : by - 6) * 256;
  const int row0 = blockIdx.x * 128;
  const int tid = threadIdx.x;
  const int lane = tid & 63;
  const int wid = tid >> 6;
  const int wm = wid >> 2;   // 0..1 (M: 64-row strip)
  const int wn = wid & 3;    // 0..3 (N: 64-col strip)
  const int l15 = lane & 15, l4 = lane >> 4;
  const int RSWZ = (l4 ^ ((l15 >> 1) & 3)) << 4;

  f32x4 acc[4][4];
#pragma unroll
  for (int i = 0; i < 4; ++i)
#pragma unroll
    for (int j = 0; j < 4; ++j) acc[i][j] = (f32x4){0.f, 0.f, 0.f, 0.f};

  // A: slot c = tid (128 rows x 4 slots); source pre-swizzled like round 9.
  const int Ar = tid >> 2;
  const int Asl = (tid & 3) ^ ((tid >> 3) & 3);
  const float* Agp = Xf + (size_t)(row0 + Ar) * 768 + Asl * 8;

  auto loadA = [&](int k0, float4& a0, float4& a1) {
    a0 = *reinterpret_cast<const float4*>(Agp + k0);
    a1 = *reinterpret_cast<const float4*>(Agp + k0 + 4);
  };
  auto writeA = [&](int bufi, const float4& a0, const float4& a1) {
    unsigned int u0, u1, u2, u3;
    CVTPK(u0, a0.x, a0.y);
    CVTPK(u1, a0.z, a0.w);
    CVTPK(u2, a1.x, a1.y);
    CVTPK(u3, a1.z, a1.w);
    int4v v = {(int)u0, (int)u1, (int)u2, (int)u3};
    *reinterpret_cast<int4v*>((char*)&lds[bufi][0] + (size_t)tid * 16) = v;
  };
  auto stageB = [&](int bufi, int k0) {
#pragma unroll
    for (int iss = 0; iss < 2; ++iss) {
      const int c = iss * 512 + tid;
      const int r = c >> 2;
      const int sl = (c & 3) ^ ((c >> 3) & 3);
      const unsigned short* gp = W + (size_t)(col0 + r) * 768 + k0 + sl * 8;
      GLD16(gp, (char*)&lds[bufi][0] + 8192 + (size_t)c * 16);
    }
  };

  {
    float4 a0, a1;
    loadA(0, a0, a1);
    stageB(0, 0);
    writeA(0, a0, a1);
  }
  asm volatile("s_waitcnt vmcnt(0) lgkmcnt(0)" ::: "memory");
  __builtin_amdgcn_s_barrier();

  for (int kt = 0; kt < 24; ++kt) {
    const int cb = kt & 1;
    float4 xa0, xa1;
    if (kt < 23) {
      loadA((kt + 1) * 32, xa0, xa1);
      stageB(cb ^ 1, (kt + 1) * 32);
    }

    const char* Ab = (const char*)&lds[cb][0];
    const char* Bb = (const char*)&lds[cb][0] + 8192;
    short8 a[4], b[4];
#pragma unroll
    for (int mt = 0; mt < 4; ++mt) {
      const int r = wm * 64 + mt * 16 + l15;
      a[mt] = *reinterpret_cast<const short8*>(Ab + r * 64 + RSWZ);
    }
#pragma unroll
    for (int nt = 0; nt < 4; ++nt) {
      const int r = wn * 64 + nt * 16 + l15;
      b[nt] = *reinterpret_cast<const short8*>(Bb + r * 64 + RSWZ);
    }
    __builtin_amdgcn_s_setprio(1);
#pragma unroll
    for (int mt = 0; mt < 4; ++mt)
#pragma unroll
      for (int nt = 0; nt < 4; ++nt)
        acc[mt][nt] = MFMA16(a[mt], b[nt], acc[mt][nt], 0, 0, 0);
    __builtin_amdgcn_s_setprio(0);
    if (kt < 23) writeA(cb ^ 1, xa0, xa1);  // cvt+ds_write late (T14)
    asm volatile("s_waitcnt vmcnt(0) lgkmcnt(0)" ::: "memory");
    __builtin_amdgcn_s_barrier();
  }

  const int mat = mode0 ? (col0 >= 768 ? 1 : 0) : ((by - 6) / 3);

  // ---- kdsq -> wq (key path, mat 0: kd cols). Head = 64-col wn strip. ----
  if (!mode0 && mat == 0) {
    const int hh = ((by - 6) << 2) + wn;  // 0..11
#pragma unroll
    for (int mt = 0; mt < 4; ++mt) {
#pragma unroll
      for (int i = 0; i < 4; ++i) {
        float s = acc[mt][0][i] * acc[mt][0][i] + acc[mt][1][i] * acc[mt][1][i] +
                  acc[mt][2][i] * acc[mt][2][i] + acc[mt][3][i] * acc[mt][3][i];
        s += __shfl_xor(s, 1);
        s += __shfl_xor(s, 2);
        s += __shfl_xor(s, 4);
        s += __shfl_xor(s, 8);
        if (l15 == 0) {
          const int row = row0 + wm * 64 + mt * 16 + l4 * 4 + i;
          const int bb = row >> 10, nn = row & 1023;
          wqf[(size_t)(bb * 12 + hh) * 1024 + nn] =
              __builtin_amdgcn_exp2f(-s * C2);
        }
      }
    }
  }

  // ---- epilogue: direct scatter (replay-proven); Vt packs short4 ----
  const int cbase = col0 - mat * 768 + wn * 64;
  const float* barr = mode0 ? bq : (mat == 2 ? bv : bk);
  if (!mode0 && mat == 2) {
#pragma unroll
    for (int nt = 0; nt < 4; ++nt) {
      const int cc = cbase + nt * 16 + l15;
      const int hh = cc >> 6, dd = cc & 63;
      const float bias = barr[cc];
#pragma unroll
      for (int mt = 0; mt < 4; ++mt) {
        const int row = row0 + wm * 64 + mt * 16 + l4 * 4;
        const int bb = row >> 10, nn = row & 1023;
        short4v pv;
#pragma unroll
        for (int i = 0; i < 4; ++i)
          pv[i] = (short)f2b(acc[mt][nt][i] + bias);
        *reinterpret_cast<short4v*>(
            Vt + ((size_t)(bb * 12 + hh) * 64 + dd) * 1024 + nn) = pv;
      }
    }
  } else {
    const float scale = mode0 ? QSC : 1.0f;
    unsigned short* outC = mode0 ? Qc : Kc;
#pragma unroll
    for (int nt = 0; nt < 4; ++nt) {
      const int cc = cbase + nt * 16 + l15;
      const int hh = cc >> 6, dd = cc & 63;
      const float bias = (mat >= 1) ? barr[cc] : 0.f;
#pragma unroll
      for (int mt = 0; mt < 4; ++mt) {
#pragma unroll
        for (int i = 0; i < 4; ++i) {
          const int row = row0 + wm * 64 + mt * 16 + l4 * 4 + i;
          const int bb = row >> 10, nn = row & 1023;
          outC[((size_t)(bb * 12 + hh) * 1024 + nn) * 128 + mat * 64 + dd] =
              f2b((acc[mt][nt][i] + bias) * scale);
        }
      }
    }
  }
}

// ---------------- flash attention: swapped-QK 32x32, in-register softmax --
// V is UNSCALED; w applied to P in-register: P = exp2(s - m) * w[key].
__global__ __launch_bounds__(256, 3) void attn_kernel(
    const unsigned short* __restrict__ Qc, const unsigned short* __restrict__ Kc,
    const unsigned short* __restrict__ Vt, const float* __restrict__ wqf,
    float* __restrict__ out) {
  __shared__ __align__(16) short kbuf[2][64 * 128];  // 32 KB, swz (row&15)<<4
  __shared__ __align__(16) short vbuf[2][64 * 64];   // 16 KB, swz (row&7)<<4
  __shared__ __align__(16) float wfb[1024];          // 4 KB

  const int bh = blockIdx.x % 96;
  const int qb = blockIdx.x / 96;
  const int b = bh / 12, h = bh - b * 12;
  const int lane = threadIdx.x & 63;
  const int w = threadIdx.x >> 6;
  const int l31 = lane & 31, l5 = lane >> 5;

  const unsigned short* Kg = Kc + (size_t)bh * 1024 * 128;
  const unsigned short* Vg = Vt + (size_t)bh * 64 * 1024;

  auto stageK = [&](int bufi, int kb) {
#pragma unroll
    for (int i = 0; i < 4; ++i) {
      const int slot = i * 256 + threadIdx.x;
      const int row = slot >> 4;
      const int d0 = ((slot & 15) ^ (row & 15)) * 8;
      const unsigned short* gp = Kg + (size_t)(kb * 64 + row) * 128 + d0;
      GLD16(gp, (char*)(&kbuf[bufi][0]) + (i * 256 + w * 64) * 16);
    }
  };
  auto stageV = [&](int bufi, int kb) {
#pragma unroll
    for (int i = 0; i < 2; ++i) {
      const int slot = i * 256 + threadIdx.x;
      const int row = slot >> 3;
      const int k0 = ((slot & 7) ^ (row & 7)) * 8;
      const unsigned short* gp = Vg + (size_t)row * 1024 + kb * 64 + k0;
      GLD16(gp, (char*)(&vbuf[bufi][0]) + (i * 256 + w * 64) * 16);
    }
  };

  stageK(0, 0);
  stageV(0, 0);
  {
    const float* gp = wqf + (size_t)bh * 1024 + threadIdx.x * 4;
    GLD16(gp, (char*)(&wfb[0]) + w * 1024);
  }

  const unsigned short* Qb =
      Qc + ((size_t)bh * 1024 + qb * 128 + w * 32 + l31) * 128 + l5 * 8;
  short8 qf[8];
#pragma unroll
  for (int s = 0; s < 8; ++s)
    qf[s] = *reinterpret_cast<const short8*>(Qb + s * 16);

  short8 ones;
#pragma unroll
  for (int j = 0; j < 8; ++j) ones[j] = (short)0x3F80;  // bf16 1.0

  f32x16 o0, o1, la;
#pragma unroll
  for (int r = 0; r < 16; ++r) {
    o0[r] = 0.f;
    o1[r] = 0.f;
    la[r] = 0.f;
  }
  float m = -1e30f;

  const int S4 = (lane & 15) << 4;
  const int S3 = (lane & 7) << 4;
  const int ko = l5 * 16;

  asm volatile("s_waitcnt vmcnt(0)" ::: "memory");
  __syncthreads();

  int buf = 0;
  for (int kb = 0; kb < 16; ++kb) {
    if (kb < 15) {
      stageK(buf ^ 1, kb + 1);
      stageV(buf ^ 1, kb + 1);
    }

    const char* kB = (const char*)(&kbuf[buf][0]) + l31 * 256;
    f32x16 s0, s1;
#pragma unroll
    for (int r = 0; r < 16; ++r) {
      s0[r] = 0.f;
      s1[r] = 0.f;
    }
    __builtin_amdgcn_s_setprio(1);
#pragma unroll
    for (int s = 0; s < 8; ++s) {
      const int off = (s * 32 + ko) ^ S4;
      short8 a0 = *reinterpret_cast<const short8*>(kB + off);
      short8 a1 = *reinterpret_cast<const short8*>(kB + 8192 + off);
      s0 = MFMA32(a0, qf[s], s0, 0, 0, 0);
      s1 = MFMA32(a1, qf[s], s1, 0, 0, 0);
    }
    __builtin_amdgcn_s_setprio(0);

    // per-key w vectors (broadcast f32x4 reads; rows crow = (r&3)+8(r>>2)+4l5)
    f32x4 w0v[4], w1v[4];
#pragma unroll
    for (int j = 0; j < 4; ++j) {
      w0v[j] = *reinterpret_cast<const f32x4*>(&wfb[kb * 64 + j * 8 + 4 * l5]);
      w1v[j] =
          *reinterpret_cast<const f32x4*>(&wfb[kb * 64 + 32 + j * 8 + 4 * l5]);
    }

    float mx = s0[0];
#pragma unroll
    for (int r = 1; r < 16; ++r) mx = fmaxf(mx, s0[r]);
#pragma unroll
    for (int r = 0; r < 16; ++r) mx = fmaxf(mx, s1[r]);
    mx = fmaxf(mx, __shfl_xor(mx, 32));

    if (!__all(mx <= m + 11.0f)) {
      const float mn = fmaxf(m, mx);
      const float c = __builtin_amdgcn_exp2f(m - mn);
      m = mn;
      float cr[16];
#pragma unroll
      for (int r = 0; r < 16; ++r)
        cr[r] = __shfl(c, (r & 3) + 8 * (r >> 2) + 4 * l5);
#pragma unroll
      for (int r = 0; r < 16; ++r) {
        la[r] *= cr[r];
        o0[r] *= cr[r];
        o1[r] *= cr[r];
      }
    }

#pragma unroll
    for (int r = 0; r < 16; ++r) {
      s0[r] = __builtin_amdgcn_exp2f(s0[r] - m) * w0v[r >> 2][r & 3];
      s1[r] = __builtin_amdgcn_exp2f(s1[r] - m) * w1v[r >> 2][r & 3];
    }
    unsigned int u[16];
#pragma unroll
    for (int j = 0; j < 8; ++j) {
      CVTPK(u[j], s0[2 * j], s0[2 * j + 1]);
      CVTPK(u[8 + j], s1[2 * j], s1[2 * j + 1]);
    }
    PLSWAP(u[0], u[2]);
    PLSWAP(u[1], u[3]);
    PLSWAP(u[4], u[6]);
    PLSWAP(u[5], u[7]);
    PLSWAP(u[8], u[10]);
    PLSWAP(u[9], u[11]);
    PLSWAP(u[12], u[14]);
    PLSWAP(u[13], u[15]);
    short8 pa[4];
    {
      int4v t0 = {(int)u[0], (int)u[1], (int)u[2], (int)u[3]};
      int4v t1 = {(int)u[4], (int)u[5], (int)u[6], (int)u[7]};
      int4v t2 = {(int)u[8], (int)u[9], (int)u[10], (int)u[11]};
      int4v t3 = {(int)u[12], (int)u[13], (int)u[14], (int)u[15]};
      pa[0] = __builtin_bit_cast(short8, t0);
      pa[1] = __builtin_bit_cast(short8, t1);
      pa[2] = __builtin_bit_cast(short8, t2);
      pa[3] = __builtin_bit_cast(short8, t3);
    }

    const char* vB = (const char*)(&vbuf[buf][0]) + l31 * 128;
    __builtin_amdgcn_s_setprio(1);
#pragma unroll
    for (int kk = 0; kk < 4; ++kk) {
      const int off = (kk * 32 + ko) ^ S3;
      short8 v0 = *reinterpret_cast<const short8*>(vB + off);
      short8 v1 = *reinterpret_cast<const short8*>(vB + 4096 + off);
      o0 = MFMA32(pa[kk], v0, o0, 0, 0, 0);
      o1 = MFMA32(pa[kk], v1, o1, 0, 0, 0);
      la = MFMA32(pa[kk], ones, la, 0, 0, 0);
    }
    __builtin_amdgcn_s_setprio(0);

    asm volatile("s_waitcnt vmcnt(0)" ::: "memory");
    __syncthreads();
    buf ^= 1;
  }

  const int qbase = b * 1024 + qb * 128 + w * 32;
#pragma unroll
  for (int r = 0; r < 16; ++r) {
    const float iv = __builtin_amdgcn_rcpf(la[r]);
    const int q = qbase + (r & 3) + 8 * (r >> 2) + 4 * l5;
    float* op = out + (size_t)q * 768 + h * 64 + l31;
    op[0] = o0[r] * iv;
    op[32] = o1[r] * iv;
  }
}

// ---------------------------------------------------------------------------
extern "C" void kernel_launch(void* const* d_in, const int* in_sizes, int n_in,
                              void* d_out, int out_size, void* d_ws,
                              size_t ws_size, hipStream_t stream) {
  const float* query = (const float*)d_in[0];
  const float* key = (const float*)d_in[1];
  const float* Wd = (const float*)d_in[2];
  const float* Wq = (const float*)d_in[3];
  const float* bq = (const float*)d_in[4];
  const float* Wk = (const float*)d_in[5];
  const float* bk = (const float*)d_in[6];
  const float* Wv = (const float*)d_in[7];
  const float* bv = (const float*)d_in[8];
  float* out = (float*)d_out;

  char* p = (char*)d_ws;
  auto alloc = [&](size_t n) {
    char* r = p;
    p += (n + 255) & ~(size_t)255;
    return r;
  };
  unsigned short* Wcq = (unsigned short*)alloc(1536ULL * 768 * 2);
  unsigned short* Wck = (unsigned short*)alloc(2304ULL * 768 * 2);
  unsigned short* Qc = (unsigned short*)alloc(96ULL * 1024 * 128 * 2);
  unsigned short* Kc = (unsigned short*)alloc(96ULL * 1024 * 128 * 2);
  unsigned short* Vt = (unsigned short*)alloc(96ULL * 64 * 1024 * 2);
  float* wqf = (float*)alloc(96ULL * 1024 * 4);

  cvtw_kernel<<<2880, 256, 0, stream>>>(Wd, Wq, Wk, Wv, Wcq, Wck);

  proj_kernel<<<dim3(64, 15), 512, 0, stream>>>(query, key, Wcq, Wck, bq, bk,
                                                bv, Qc, Kc, Vt, wqf);

  attn_kernel<<<768, 256, 0, stream>>>(Qc, Kc, Vt, wqf, out);
}